// Round 5
// baseline (850.459 us; speedup 1.0000x reference)
//
#include <hip/hip_runtime.h>
#include <hip/hip_bf16.h>
#include <cstdint>

#define B_SZ 1000
#define D_SZ 512
#define N_SZ 100000
#define F_SZ 50
#define NEGV -1000000.0f

#define NT2_B 4       // b-groups of 256
#define NT2_N 1564    // n-groups of 64  (1564*64 = 100096)
#define CAP 64

#define T_OFF 0
#define CNT_OFF 4096
#define ENT_OFF 32768          // 6256*64*4 = 1.6 MB, ends < 2 MB
#define QB_OFF  0x200000       // qb: 1024*512*2 = 1 MB
#define RT_OFF  0x400000       // rhsT: 100096*512*2 = 102.5 MB
#define RT_ROWS 100096

typedef __bf16 bf16x8 __attribute__((ext_vector_type(8)));
typedef float f32x4 __attribute__((ext_vector_type(4)));

// ---------------- zero t/cnt regions (ws poisoned 0xAA each call) ----------
__global__ void zero_ws(int* p){ p[blockIdx.x * 256 + threadIdx.x] = 0; }

// ---------------- q f32 [1000][512] -> qb bf16 [1024][512], pad rows 0 -----
__global__ void cvtq_kernel(const float* __restrict__ q, __bf16* __restrict__ qb){
  int g = blockIdx.x * 256 + threadIdx.x;
  int row = g >> 6;
  int k0 = (g & 63) * 8;
  float4 v0 = make_float4(0.f,0.f,0.f,0.f), v1 = v0;
  if(row < B_SZ){
    v0 = *(const float4*)(q + (size_t)row * D_SZ + k0);
    v1 = *(const float4*)(q + (size_t)row * D_SZ + k0 + 4);
  }
  bf16x8 w = { (__bf16)v0.x,(__bf16)v0.y,(__bf16)v0.z,(__bf16)v0.w,
               (__bf16)v1.x,(__bf16)v1.y,(__bf16)v1.z,(__bf16)v1.w };
  *(bf16x8*)(qb + (size_t)row * D_SZ + k0) = w;
}

// ---------------- rhs f32 [512][100000] -> rhsT bf16 [100096][512] ---------
__global__ __launch_bounds__(256)
void tconv_kernel(const float* __restrict__ rhs, __bf16* __restrict__ rhsT){
  __shared__ float tile[64][65];
  const int tn = blockIdx.x;           // 0..1563
  const int tk = blockIdx.y;           // 0..7
  const int tid = threadIdx.x;
  const int n0 = tn * 64, k0 = tk * 64;
  {
    const int nc = (tid & 15) * 4;
    const int kr0 = tid >> 4;
    #pragma unroll
    for(int i = 0; i < 4; i++){
      int kr = kr0 + i * 16;
      int n = n0 + nc;
      float4 v = (n < N_SZ) ? *(const float4*)(rhs + (size_t)(k0 + kr) * N_SZ + n)
                            : make_float4(0.f,0.f,0.f,0.f);
      tile[kr][nc+0] = v.x; tile[kr][nc+1] = v.y;
      tile[kr][nc+2] = v.z; tile[kr][nc+3] = v.w;
    }
  }
  __syncthreads();
  {
    const int nl = tid >> 2;
    const int kc = (tid & 3) * 16;
    float a[16];
    #pragma unroll
    for(int j = 0; j < 16; j++) a[j] = tile[kc + j][nl];
    bf16x8 w0, w1;
    #pragma unroll
    for(int j = 0; j < 8; j++){ w0[j] = (__bf16)a[j]; w1[j] = (__bf16)a[8 + j]; }
    __bf16* dst = rhsT + (size_t)(n0 + nl) * D_SZ + k0 + kc;
    *(bf16x8*)dst = w0;
    *(bf16x8*)(dst + 8) = w1;
  }
}

// ---------------- t[b] = q[b] . rhs[:, target[b]] (f32 exact) --------------
__global__ void t_kernel(const float* __restrict__ q, const float* __restrict__ rhs,
                         const int* __restrict__ target, float* __restrict__ t){
  int b = blockIdx.x;
  int tid = threadIdx.x;
  int tj = target[b];
  const float* qb = q + (size_t)b * D_SZ;
  float p = qb[tid] * rhs[(size_t)tid * N_SZ + tj]
          + qb[tid + 256] * rhs[(size_t)(tid + 256) * N_SZ + tj];
  for(int off = 32; off; off >>= 1) p += __shfl_down(p, off);
  __shared__ float red[4];
  if((tid & 63) == 0) red[tid >> 6] = p;
  __syncthreads();
  if(tid == 0) t[b] = red[0] + red[1] + red[2] + red[3];
}

// ---------------- dedupe filter∪target, bin into owning block --------------
// bins keyed by (b>>8, j>>6) to match main kernel geometry (256b x 64n)
__global__ void prep_kernel(const int* __restrict__ filt, const int* __restrict__ target,
                            const float* __restrict__ t, int* __restrict__ cnt,
                            unsigned* __restrict__ entries, float* __restrict__ out){
  int b = blockIdx.x * blockDim.x + threadIdx.x;
  if(b >= B_SZ) return;
  int idx[F_SZ + 1];
  for(int i = 0; i < F_SZ; i++) idx[i] = filt[b * F_SZ + i];
  idx[F_SZ] = target[b];
  float tb = t[b];
  int nuniq = 0;
  for(int i = 0; i <= F_SZ; i++){
    int j = idx[i];
    bool first = true;
    for(int k = 0; k < i; k++) if(idx[k] == j){ first = false; break; }
    if(!first) continue;
    nuniq++;
    int bid = (b >> 8) * NT2_N + (j >> 6);
    int pos = atomicAdd(&cnt[bid], 1);
    if(pos < CAP)
      entries[(size_t)bid * CAP + pos] = (unsigned)(((b & 255) << 6) | (j & 63));
  }
  out[b] = 1.0f + ((NEGV >= tb) ? (float)nuniq : 0.0f);
}

// ---------------- barrier-free per-wave MFMA GEMM + rank count -------------
// block = 4 waves stacked in b (256b x 64n); each wave owns 64b x 64n.
// Fragments loaded straight from global (bf16 [row][k]): one bf16x8 frag
// load = 16 fully-used 64B lines (4 quads tile each line). No LDS, no
// __syncthreads -> no vmcnt(0) drain anywhere. Ping-pong frag prefetch.
__global__ __launch_bounds__(256, 3)
void main_kernel(const __bf16* __restrict__ rhsT, const __bf16* __restrict__ qb,
                 const float* __restrict__ t, const int* __restrict__ cnt,
                 const unsigned* __restrict__ entries, float* __restrict__ out){
  const int tb = blockIdx.x;        // fastest -> 4 sharers of B co-dispatch
  const int tn = blockIdx.y;
  const int bid = tb * NT2_N + tn;
  const int tid = threadIdx.x;
  const int wave = tid >> 6, lane = tid & 63;
  const int quad = lane >> 4, l15 = lane & 15;
  const int b0 = tb * 256 + wave * 64;   // wave's first row
  const int n0 = tn * 64;

  const __bf16* aP = qb   + (size_t)(b0 + l15) * D_SZ + quad * 8;
  const __bf16* bP = rhsT + (size_t)(n0 + l15) * D_SZ + quad * 8;

  f32x4 acc[4][4];
  #pragma unroll
  for(int r = 0; r < 4; r++)
    #pragma unroll
    for(int c = 0; c < 4; c++)
      acc[r][c] = (f32x4){0.f, 0.f, 0.f, 0.f};

  bf16x8 fa[2][4], fb[2][4];
  #define LOADF(S, KT) do{ \
    _Pragma("unroll") \
    for(int r_ = 0; r_ < 4; r_++) fa[S][r_] = *(const bf16x8*)(aP + r_ * 16 * D_SZ + (KT) * 32); \
    _Pragma("unroll") \
    for(int c_ = 0; c_ < 4; c_++) fb[S][c_] = *(const bf16x8*)(bP + c_ * 16 * D_SZ + (KT) * 32); \
  } while(0)

  LOADF(0, 0);
  #pragma unroll
  for(int kt = 0; kt < 16; kt++){
    const int cur = kt & 1;
    if(kt < 15) LOADF(cur ^ 1, kt + 1);
    #pragma unroll
    for(int r = 0; r < 4; r++)
      #pragma unroll
      for(int c = 0; c < 4; c++)
        acc[r][c] = __builtin_amdgcn_mfma_f32_16x16x32_bf16(fa[cur][r], fb[cur][c], acc[r][c], 0, 0, 0);
  }
  #undef LOADF

  // ---- count s >= t_b  (C/D layout: col=lane&15, row=quad*4+reg) ----
  int cntv[4][4];
  float trow[4][4];
  #pragma unroll
  for(int rt = 0; rt < 4; rt++){
    #pragma unroll
    for(int rg = 0; rg < 4; rg++){
      int bg = b0 + rt * 16 + quad * 4 + rg;
      float tv = (bg < B_SZ) ? t[bg] : __builtin_inff();
      trow[rt][rg] = tv;
      int c = 0;
      #pragma unroll
      for(int ct = 0; ct < 4; ct++){
        int ncol = n0 + ct * 16 + l15;
        if(ncol < N_SZ && acc[rt][ct][rg] >= tv) c++;
      }
      cntv[rt][rg] = c;
    }
  }

  // ---- subtract filtered entries owned by this wave ----
  int lc = cnt[bid]; if(lc > CAP) lc = CAP;
  for(int e = 0; e < lc; e++){
    unsigned en = entries[(size_t)bid * CAP + e];
    int row256 = en >> 6;
    if((row256 >> 6) != wave) continue;
    int rowl = row256 & 63;
    int col  = en & 63;
    int rt_e = rowl >> 4, q_e = (rowl & 15) >> 2, rg_e = rowl & 3;
    int ct_e = col >> 4,  c15 = col & 15;
    if(quad == q_e && l15 == c15){
      #pragma unroll
      for(int rt = 0; rt < 4; rt++)
        #pragma unroll
        for(int ct = 0; ct < 4; ct++)
          #pragma unroll
          for(int rg = 0; rg < 4; rg++)
            if(rt == rt_e && ct == ct_e && rg == rg_e &&
               acc[rt][ct][rg] >= trow[rt][rg])
              cntv[rt][rg]--;
    }
  }

  // ---- 16-lane column reduce, one atomic per row ----
  #pragma unroll
  for(int rt = 0; rt < 4; rt++){
    #pragma unroll
    for(int rg = 0; rg < 4; rg++){
      int c = cntv[rt][rg];
      c += __shfl_xor(c, 1);
      c += __shfl_xor(c, 2);
      c += __shfl_xor(c, 4);
      c += __shfl_xor(c, 8);
      if(l15 == 0){
        int bg = b0 + rt * 16 + quad * 4 + rg;
        if(bg < B_SZ) atomicAdd(&out[bg], (float)c);
      }
    }
  }
}

extern "C" void kernel_launch(void* const* d_in, const int* in_sizes, int n_in,
                              void* d_out, int out_size, void* d_ws, size_t ws_size,
                              hipStream_t stream){
  const float* q    = (const float*)d_in[0];
  const float* rhs  = (const float*)d_in[1];
  const int* filt   = (const int*)d_in[2];
  const int* target = (const int*)d_in[3];
  float* out = (float*)d_out;
  char* ws = (char*)d_ws;
  float* t          = (float*)(ws + T_OFF);
  int* cnt          = (int*)(ws + CNT_OFF);
  unsigned* entries = (unsigned*)(ws + ENT_OFF);
  __bf16* qb        = (__bf16*)(ws + QB_OFF);
  __bf16* rhsT      = (__bf16*)(ws + RT_OFF);

  zero_ws<<<32, 256, 0, stream>>>((int*)ws);                     // t + cnt (29.1 KB)
  cvtq_kernel<<<256, 256, 0, stream>>>(q, qb);
  tconv_kernel<<<dim3(RT_ROWS / 64, 8), 256, 0, stream>>>(rhs, rhsT);
  t_kernel<<<B_SZ, 256, 0, stream>>>(q, rhs, target, t);
  prep_kernel<<<(B_SZ + 255) / 256, 256, 0, stream>>>(filt, target, t, cnt, entries, out);
  main_kernel<<<dim3(NT2_B, NT2_N), 256, 0, stream>>>(rhsT, qb, t, cnt, entries, out);
}

// Round 6
// 808.598 us; speedup vs baseline: 1.0518x; 1.0518x over previous
//
#include <hip/hip_runtime.h>
#include <hip/hip_bf16.h>
#include <cstdint>

#define B_SZ 1000
#define D_SZ 512
#define N_SZ 100000
#define F_SZ 50

#define NB   1564          // n-chunks of 64 cols (1564*64 = 100096)
#define CAPY 96            // entries per n-chunk bin (lambda ~32.6 -> overflow ~1e-18)

#define PART_OFF 0         // 8*1024*4 = 32768
#define CNT_OFF  32768     // 1564*4 = 6256
#define T_OFF    40960     // 1024*4
#define ENT_OFF  65536     // 1564*96*4 = 600576
#define QB_OFF   0x100000  // 1 MB: qb bf16 1024*512*2
// ws use: 2 MB total

typedef __bf16 bf16x8 __attribute__((ext_vector_type(8)));
typedef __bf16 bf16x2 __attribute__((ext_vector_type(2)));
typedef float f32x4 __attribute__((ext_vector_type(4)));

__device__ __forceinline__ float f4c(const float4& v, int c){
  switch(c){ case 0: return v.x; case 1: return v.y; case 2: return v.z; default: return v.w; }
}

// ---------------- zero part/cnt regions (ws poisoned 0xAA each call) -------
__global__ void zero_ws(int* p){ p[blockIdx.x * 256 + threadIdx.x] = 0; }

// ---------------- q f32 [1000][512] -> qb bf16 [1024][512], pad rows 0 -----
__global__ void cvtq_kernel(const float* __restrict__ q, __bf16* __restrict__ qb){
  int g = blockIdx.x * 256 + threadIdx.x;
  int row = g >> 6;
  int k0 = (g & 63) * 8;
  float4 v0 = make_float4(0.f,0.f,0.f,0.f), v1 = v0;
  if(row < B_SZ){
    v0 = *(const float4*)(q + (size_t)row * D_SZ + k0);
    v1 = *(const float4*)(q + (size_t)row * D_SZ + k0 + 4);
  }
  bf16x8 w = { (__bf16)v0.x,(__bf16)v0.y,(__bf16)v0.z,(__bf16)v0.w,
               (__bf16)v1.x,(__bf16)v1.y,(__bf16)v1.z,(__bf16)v1.w };
  *(bf16x8*)(qb + (size_t)row * D_SZ + k0) = w;
}

// ---------------- t[b] = q[b] . rhs[:, target[b]] (f32 exact) --------------
__global__ void t_kernel(const float* __restrict__ q, const float* __restrict__ rhs,
                         const int* __restrict__ target, float* __restrict__ t){
  int b = blockIdx.x;
  int tid = threadIdx.x;
  int tj = target[b];
  const float* qb = q + (size_t)b * D_SZ;
  float p = qb[tid] * rhs[(size_t)tid * N_SZ + tj]
          + qb[tid + 256] * rhs[(size_t)(tid + 256) * N_SZ + tj];
  for(int off = 32; off; off >>= 1) p += __shfl_down(p, off);
  __shared__ float red[4];
  if((tid & 63) == 0) red[tid >> 6] = p;
  __syncthreads();
  if(tid == 0) t[b] = red[0] + red[1] + red[2] + red[3];
}

// ---------------- dedupe filter∪target, bin by n-chunk ---------------------
__global__ void prep_kernel(const int* __restrict__ filt, const int* __restrict__ target,
                            int* __restrict__ cnt, unsigned* __restrict__ entries){
  int b = blockIdx.x * blockDim.x + threadIdx.x;
  if(b >= B_SZ) return;
  int idx[F_SZ + 1];
  for(int i = 0; i < F_SZ; i++) idx[i] = filt[b * F_SZ + i];
  idx[F_SZ] = target[b];
  for(int i = 0; i <= F_SZ; i++){
    int j = idx[i];
    bool first = true;
    for(int k = 0; k < i; k++) if(idx[k] == j){ first = false; break; }
    if(!first) continue;
    int bid = j >> 6;
    int pos = atomicAdd(&cnt[bid], 1);
    if(pos < CAPY)
      entries[(size_t)bid * CAPY + pos] = (unsigned)((b << 6) | (j & 63));
  }
}

// ---------------- B-stationary fused GEMM + rank count ---------------------
// 1564 blocks (one 64-col n-chunk each, B read ONCE); 512 thr = 8 waves;
// wave w owns rows [128w,128w+128) x all 64 cols: acc 8x4 tiles = 128 AGPR.
// B: f32 global -> VGPR (2-kt-deep pipe) -> cvt -> LDS dbuf (k-paired pairs,
// 1 barrier/kt). A: bf16 qb (L2-resident), frags straight to VGPR, 1-kt pipe.
__global__ __launch_bounds__(512, 2)
void main_kernel(const float* __restrict__ rhs, const __bf16* __restrict__ qb,
                 const float* __restrict__ t, const int* __restrict__ cnt,
                 const unsigned* __restrict__ entries, float* __restrict__ part){
  __shared__ __bf16 Bb[2][64][34];   // stride 34: writes 2-way (free), frag b128 ~2-way
  __shared__ float tl[1024];
  __shared__ float tle[CAPY];
  __shared__ unsigned lent[CAPY];
  __shared__ int lcnt_s;

  const int tn = blockIdx.x;
  const int n0 = tn * 64;
  const int tid = threadIdx.x;
  const int wave = tid >> 6, lane = tid & 63;
  const int quad = lane >> 4, l15 = lane & 15;

  // ---- B stager ids (threads 0..255): kp = k-pair, c4 = col group ----
  const int kp = tid >> 4;          // 0..15 (k rows 2kp, 2kp+1) [only tid<256 valid use]
  const int c4 = (tid & 15) * 4;
  const bool bok = (n0 + c4 + 3) < N_SZ;
  const float* pB = rhs + (size_t)(2 * (kp & 15)) * N_SZ + n0 + c4;
  const float4 fz = make_float4(0.f, 0.f, 0.f, 0.f);

  // ---- A pointers ----
  const __bf16* aP = qb + (size_t)(128 * wave + l15) * D_SZ + quad * 8;
  const __bf16* aPn = aP + 32;      // next-kt base

  // ---- prologue: issue deep prefetch first ----
  float4 lo0, hi0, lo1, hi1;
  lo0 = (tid < 256 && bok) ? *(const float4*)pB : fz;
  hi0 = (tid < 256 && bok) ? *(const float4*)(pB + N_SZ) : fz;
  lo1 = (tid < 256 && bok) ? *(const float4*)(pB + (size_t)32 * N_SZ) : fz;
  hi1 = (tid < 256 && bok) ? *(const float4*)(pB + (size_t)33 * N_SZ) : fz;
  pB += (size_t)64 * N_SZ;          // now points at kt=2
  bf16x8 A0[8], A1[8];
  #pragma unroll
  for(int rt = 0; rt < 8; rt++) A0[rt] = *(const bf16x8*)(aP + rt * 16 * D_SZ);

  // ---- LDS metadata fills ----
  tl[tid] = t[tid];
  tl[tid + 512] = t[tid + 512];
  if(tid == 0){ int c = cnt[tn]; lcnt_s = (c > CAPY) ? CAPY : c; }
  if(tid < CAPY) lent[tid] = entries[(size_t)tn * CAPY + tid];
  __syncthreads();
  if(tid < lcnt_s) tle[tid] = tl[lent[tid] >> 6];

  f32x4 acc[8][4];
  #pragma unroll
  for(int rt = 0; rt < 8; rt++)
    #pragma unroll
    for(int ct = 0; ct < 4; ct++)
      acc[rt][ct] = (f32x4){0.f, 0.f, 0.f, 0.f};

  #define BODY(KTV, PP, ACUR, ANXT) do{ \
    if(tid < 256){ \
      _Pragma("unroll") \
      for(int i = 0; i < 4; i++){ \
        bf16x2 w_ = { (__bf16)f4c(lo##PP, i), (__bf16)f4c(hi##PP, i) }; \
        *(bf16x2*)&Bb[PP][c4 + i][2 * kp] = w_; \
      } \
      if((KTV) < 14){ \
        lo##PP = bok ? *(const float4*)pB : fz; \
        hi##PP = bok ? *(const float4*)(pB + N_SZ) : fz; \
        pB += (size_t)32 * N_SZ; \
      } \
    } \
    if((KTV) < 15){ \
      _Pragma("unroll") \
      for(int rt = 0; rt < 8; rt++) ANXT[rt] = *(const bf16x8*)(aPn + rt * 16 * D_SZ); \
      aPn += 32; \
    } \
    __syncthreads(); \
    bf16x8 bfr[4]; \
    _Pragma("unroll") \
    for(int ct = 0; ct < 4; ct++) bfr[ct] = *(bf16x8*)&Bb[PP][ct * 16 + l15][quad * 8]; \
    _Pragma("unroll") \
    for(int rt = 0; rt < 8; rt++) \
      _Pragma("unroll") \
      for(int ct = 0; ct < 4; ct++) \
        acc[rt][ct] = __builtin_amdgcn_mfma_f32_16x16x32_bf16(ACUR[rt], bfr[ct], acc[rt][ct], 0, 0, 0); \
  }while(0)

  for(int kt = 0; kt < 16; kt += 2){
    BODY(kt,     0, A0, A1);
    BODY(kt + 1, 1, A1, A0);
  }
  #undef BODY

  // ---- count s >= t_b (C/D: col=lane&15, row=quad*4+reg; verified m89/m91)
  int cv[8][4];
  #pragma unroll
  for(int rt = 0; rt < 8; rt++)
    #pragma unroll
    for(int rg = 0; rg < 4; rg++){
      float trw = tl[128 * wave + rt * 16 + quad * 4 + rg];
      int c = 0;
      #pragma unroll
      for(int ct = 0; ct < 4; ct++){
        int ncol = n0 + ct * 16 + l15;
        if(ncol < N_SZ && acc[rt][ct][rg] >= trw) c++;
      }
      cv[rt][rg] = c;
    }

  // ---- subtract filtered entries (scalar-uniform branch tree) ----
  int lc = lcnt_s;
  for(int e = 0; e < lc; e++){
    unsigned ee = __builtin_amdgcn_readfirstlane(lent[e]);
    int b_e = (int)(ee >> 6);
    if((b_e >> 7) != wave) continue;       // wave-uniform skip
    int loc = b_e & 127;
    int rt_e = loc >> 4, qe = (loc >> 2) & 3, rg_e = loc & 3;
    int col6 = (int)(ee & 63);
    int ct_e = col6 >> 4, le = col6 & 15;
    float te = tle[e];
    bool lm = (quad == qe) && (l15 == le);
    #define LEAF(R,C,G) case G: if(lm && acc[R][C][G] >= te) cv[R][G]--; break;
    #define SWG(R,C) case C: switch(rg_e){ LEAF(R,C,0) LEAF(R,C,1) LEAF(R,C,2) LEAF(R,C,3) } break;
    #define SWC(R) case R: switch(ct_e){ SWG(R,0) SWG(R,1) SWG(R,2) SWG(R,3) } break;
    switch(rt_e){ SWC(0) SWC(1) SWC(2) SWC(3) SWC(4) SWC(5) SWC(6) SWC(7) }
    #undef SWC
    #undef SWG
    #undef LEAF
  }

  // ---- 16-lane column reduce, one atomic per (row, block) into 8-way parts
  float* pp = part + ((tn & 7) << 10);
  #pragma unroll
  for(int rt = 0; rt < 8; rt++)
    #pragma unroll
    for(int rg = 0; rg < 4; rg++){
      int c = cv[rt][rg];
      c += __shfl_xor(c, 1);
      c += __shfl_xor(c, 2);
      c += __shfl_xor(c, 4);
      c += __shfl_xor(c, 8);
      if(l15 == 0){
        int row = 128 * wave + rt * 16 + quad * 4 + rg;
        if(row < B_SZ) atomicAdd(&pp[row], (float)c);
      }
    }
}

// ---------------- out[b] = 1 + sum of 8 parts ------------------------------
__global__ void final_kernel(const float* __restrict__ part, float* __restrict__ out){
  int b = blockIdx.x * 256 + threadIdx.x;
  if(b >= B_SZ) return;
  float s = 1.0f;
  #pragma unroll
  for(int p = 0; p < 8; p++) s += part[p * 1024 + b];
  out[b] = s;
}

extern "C" void kernel_launch(void* const* d_in, const int* in_sizes, int n_in,
                              void* d_out, int out_size, void* d_ws, size_t ws_size,
                              hipStream_t stream){
  const float* q    = (const float*)d_in[0];
  const float* rhs  = (const float*)d_in[1];
  const int* filt   = (const int*)d_in[2];
  const int* target = (const int*)d_in[3];
  float* out = (float*)d_out;
  char* ws = (char*)d_ws;
  float* part       = (float*)(ws + PART_OFF);
  int* cnt          = (int*)(ws + CNT_OFF);
  float* t          = (float*)(ws + T_OFF);
  unsigned* entries = (unsigned*)(ws + ENT_OFF);
  __bf16* qb        = (__bf16*)(ws + QB_OFF);
  // ws use: 2 MB

  zero_ws<<<40, 256, 0, stream>>>((int*)ws);                 // part + cnt (40 KB)
  cvtq_kernel<<<256, 256, 0, stream>>>(q, qb);
  t_kernel<<<B_SZ, 256, 0, stream>>>(q, rhs, target, t);
  prep_kernel<<<(B_SZ + 255) / 256, 256, 0, stream>>>(filt, target, cnt, entries);
  main_kernel<<<NB, 512, 0, stream>>>(rhs, qb, t, cnt, entries, part);
  final_kernel<<<4, 256, 0, stream>>>(part, out);
}

// Round 7
// 779.824 us; speedup vs baseline: 1.0906x; 1.0369x over previous
//
#include <hip/hip_runtime.h>
#include <hip/hip_bf16.h>
#include <cstdint>

#define B_SZ 1000
#define D_SZ 512
#define N_SZ 100000
#define F_SZ 50

#define NB   1563          // n-chunks of 64 cols (1563*64 = 100032 >= 100000)
#define CAPY 96            // entries per n-chunk bin (lambda ~32.6)

#define PART_OFF 0         // 8*1024*4 = 32768
#define CNT_OFF  32768     // 1563*4 = 6252
#define T_OFF    40960     // 1024*4
#define ENT_OFF  65536     // 1563*96*4 = 600192
#define QB_OFF   0x100000  // 1 MB: qb bf16 1024*512*2
// ws use: 2 MB total

typedef __bf16 bf16x8 __attribute__((ext_vector_type(8)));
typedef __bf16 bf16x2 __attribute__((ext_vector_type(2)));
typedef float f32x4 __attribute__((ext_vector_type(4)));

__device__ __forceinline__ float f4c(const float4& v, int c){
  switch(c){ case 0: return v.x; case 1: return v.y; case 2: return v.z; default: return v.w; }
}

// ---------------- zero part/cnt regions (ws poisoned 0xAA each call) -------
__global__ void zero_ws(int* p){ p[blockIdx.x * 256 + threadIdx.x] = 0; }

// ---------------- q f32 [1000][512] -> qb bf16 [1024][512], pad rows 0 -----
__global__ void cvtq_kernel(const float* __restrict__ q, __bf16* __restrict__ qb){
  int g = blockIdx.x * 256 + threadIdx.x;
  int row = g >> 6;
  int k0 = (g & 63) * 8;
  float4 v0 = make_float4(0.f,0.f,0.f,0.f), v1 = v0;
  if(row < B_SZ){
    v0 = *(const float4*)(q + (size_t)row * D_SZ + k0);
    v1 = *(const float4*)(q + (size_t)row * D_SZ + k0 + 4);
  }
  bf16x8 w = { (__bf16)v0.x,(__bf16)v0.y,(__bf16)v0.z,(__bf16)v0.w,
               (__bf16)v1.x,(__bf16)v1.y,(__bf16)v1.z,(__bf16)v1.w };
  *(bf16x8*)(qb + (size_t)row * D_SZ + k0) = w;
}

// ---------------- t[b] = q[b] . rhs[:, target[b]] (f32 exact) --------------
__global__ void t_kernel(const float* __restrict__ q, const float* __restrict__ rhs,
                         const int* __restrict__ target, float* __restrict__ t){
  int b = blockIdx.x;
  int tid = threadIdx.x;
  int tj = target[b];
  const float* qb = q + (size_t)b * D_SZ;
  float p = qb[tid] * rhs[(size_t)tid * N_SZ + tj]
          + qb[tid + 256] * rhs[(size_t)(tid + 256) * N_SZ + tj];
  for(int off = 32; off; off >>= 1) p += __shfl_down(p, off);
  __shared__ float red[4];
  if((tid & 63) == 0) red[tid >> 6] = p;
  __syncthreads();
  if(tid == 0) t[b] = red[0] + red[1] + red[2] + red[3];
}

// ---------------- dedupe filter∪target, bin by n-chunk ---------------------
__global__ void prep_kernel(const int* __restrict__ filt, const int* __restrict__ target,
                            int* __restrict__ cnt, unsigned* __restrict__ entries){
  int b = blockIdx.x * blockDim.x + threadIdx.x;
  if(b >= B_SZ) return;
  int idx[F_SZ + 1];
  for(int i = 0; i < F_SZ; i++) idx[i] = filt[b * F_SZ + i];
  idx[F_SZ] = target[b];
  for(int i = 0; i <= F_SZ; i++){
    int j = idx[i];
    bool first = true;
    for(int k = 0; k < i; k++) if(idx[k] == j){ first = false; break; }
    if(!first) continue;
    int bid = j >> 6;
    int pos = atomicAdd(&cnt[bid], 1);
    if(pos < CAPY)
      entries[(size_t)bid * CAPY + pos] = (unsigned)((b << 6) | (j & 63));
  }
}

// ---------------- B-stationary fused GEMM + rank count ---------------------
// grid (2 b-groups x 1563 n-chunks); 512 thr = 8 waves; wave owns 64 rows
// x 64 cols (acc 4x4 = 64 regs -> no spill, 3 waves/SIMD). B: f32 global
// -> VGPR (2-kt pipe) -> cvt -> LDS slot-layout dbuf (0-conflict frag
// reads, R4-measured). A: bf16 qb, frags straight from global (L2-hot),
// issued before the barrier so the barrier wait hides their latency.
__global__ __launch_bounds__(512, 3)
void main_kernel(const float* __restrict__ rhs, const __bf16* __restrict__ qb,
                 const float* __restrict__ t, const int* __restrict__ cnt,
                 const unsigned* __restrict__ entries, float* __restrict__ part){
  // slot layout: 16B slot s = kq*64 + col  (kq = k-octet 0..3), elem = s*8 + (k&7)
  __shared__ __bf16 Bb[2][2048];    // 2 x 4 KB
  __shared__ float tl[512];
  __shared__ float tle[CAPY];
  __shared__ unsigned lent[CAPY];
  __shared__ int lcnt_s;

  const int bg = blockIdx.x;        // b-group (512 rows); fastest -> co-dispatch
  const int tn = blockIdx.y;
  const int n0 = tn * 64;
  const int tid = threadIdx.x;
  const int wave = tid >> 6, lane = tid & 63;
  const int quad = lane >> 4, l15 = lane & 15;
  const int r0 = bg * 512 + wave * 64;    // wave's first global row

  // ---- B stager ids (tid<256): kp = k-pair 0..15, c4 = col group ----
  const int kp = (tid & 255) >> 4;
  const int c4 = (tid & 15) * 4;
  const bool stg = tid < 256;
  const bool bok = stg && (n0 + c4 + 3) < N_SZ;
  const float* pB = rhs + (size_t)(2 * kp) * N_SZ + n0 + c4;
  const float4 fz = make_float4(0.f, 0.f, 0.f, 0.f);

  // ---- A pointer ----
  const __bf16* aP = qb + (size_t)(r0 + l15) * D_SZ + quad * 8;

  // ---- prologue: 2-kt-deep B prefetch ----
  float4 lo0, hi0, lo1, hi1;
  lo0 = bok ? *(const float4*)pB : fz;
  hi0 = bok ? *(const float4*)(pB + N_SZ) : fz;
  lo1 = bok ? *(const float4*)(pB + (size_t)32 * N_SZ) : fz;
  hi1 = bok ? *(const float4*)(pB + (size_t)33 * N_SZ) : fz;
  pB += (size_t)64 * N_SZ;

  // ---- metadata ----
  if(tid < 512) tl[tid] = t[bg * 512 + tid];      // t[] is 1024 floats
  if(tid == 0){ int c = cnt[tn]; lcnt_s = (c > CAPY) ? CAPY : c; }
  if(tid >= 512 - CAPY){ int e = tid - (512 - CAPY);
    lent[e] = entries[(size_t)tn * CAPY + e]; }
  __syncthreads();
  if(tid < lcnt_s) tle[tid] = t[lent[tid] >> 6];  // global read, any row

  f32x4 acc[4][4];
  #pragma unroll
  for(int rt = 0; rt < 4; rt++)
    #pragma unroll
    for(int ct = 0; ct < 4; ct++)
      acc[rt][ct] = (f32x4){0.f, 0.f, 0.f, 0.f};

  #define BODY(KTV, PP) do{ \
    if(stg){ \
      _Pragma("unroll") \
      for(int i = 0; i < 4; i++){ \
        bf16x2 w_ = { (__bf16)f4c(lo##PP, i), (__bf16)f4c(hi##PP, i) }; \
        *(bf16x2*)&Bb[PP][(kp >> 2) * 512 + (c4 + i) * 8 + 2 * (kp & 3)] = w_; \
      } \
      if((KTV) < 14){ \
        lo##PP = bok ? *(const float4*)pB : fz; \
        hi##PP = bok ? *(const float4*)(pB + N_SZ) : fz; \
        pB += (size_t)32 * N_SZ; \
      } \
    } \
    bf16x8 af[4]; \
    _Pragma("unroll") \
    for(int rt = 0; rt < 4; rt++) \
      af[rt] = *(const bf16x8*)(aP + (size_t)rt * 16 * D_SZ + (KTV) * 32); \
    __syncthreads(); \
    bf16x8 bfr[4]; \
    _Pragma("unroll") \
    for(int ct = 0; ct < 4; ct++) \
      bfr[ct] = *(bf16x8*)&Bb[PP][quad * 512 + (ct * 16 + l15) * 8]; \
    _Pragma("unroll") \
    for(int rt = 0; rt < 4; rt++) \
      _Pragma("unroll") \
      for(int ct = 0; ct < 4; ct++) \
        acc[rt][ct] = __builtin_amdgcn_mfma_f32_16x16x32_bf16(af[rt], bfr[ct], acc[rt][ct], 0, 0, 0); \
  }while(0)

  for(int kt = 0; kt < 16; kt += 2){
    BODY(kt,     0);
    BODY(kt + 1, 1);
  }
  #undef BODY

  // ---- count s >= t_b (C/D: col=lane&15, row=quad*4+reg; verified m89/m91)
  int cv[4][4];
  #pragma unroll
  for(int rt = 0; rt < 4; rt++)
    #pragma unroll
    for(int rg = 0; rg < 4; rg++){
      float trw = tl[wave * 64 + rt * 16 + quad * 4 + rg];
      int c = 0;
      #pragma unroll
      for(int ct = 0; ct < 4; ct++){
        int ncol = n0 + ct * 16 + l15;
        if(ncol < N_SZ && acc[rt][ct][rg] >= trw) c++;
      }
      cv[rt][rg] = c;
    }

  // ---- subtract filtered entries (wave-uniform scalar branch tree) ----
  int lc = lcnt_s;
  for(int e = 0; e < lc; e++){
    unsigned ee = __builtin_amdgcn_readfirstlane(lent[e]);
    int rel = (int)(ee >> 6) - r0;
    if((unsigned)rel >= 64u) continue;            // wave-uniform skip
    int rt_e = rel >> 4, qe = (rel >> 2) & 3, rg_e = rel & 3;
    int col6 = (int)(ee & 63);
    int ct_e = col6 >> 4, le = col6 & 15;
    float te = tle[e];
    bool lm = (quad == qe) && (l15 == le);
    #define LEAF(R,C,G) case G: if(lm && acc[R][C][G] >= te) cv[R][G]--; break;
    #define SWG(R,C) case C: switch(rg_e){ LEAF(R,C,0) LEAF(R,C,1) LEAF(R,C,2) LEAF(R,C,3) } break;
    #define SWC(R) case R: switch(ct_e){ SWG(R,0) SWG(R,1) SWG(R,2) SWG(R,3) } break;
    switch(rt_e){ SWC(0) SWC(1) SWC(2) SWC(3) }
    #undef SWC
    #undef SWG
    #undef LEAF
  }

  // ---- 16-lane column reduce, one atomic per row into 8-way parts ----
  float* pp = part + ((tn & 7) << 10);
  #pragma unroll
  for(int rt = 0; rt < 4; rt++)
    #pragma unroll
    for(int rg = 0; rg < 4; rg++){
      int c = cv[rt][rg];
      c += __shfl_xor(c, 1);
      c += __shfl_xor(c, 2);
      c += __shfl_xor(c, 4);
      c += __shfl_xor(c, 8);
      if(l15 == 0){
        int row = r0 + rt * 16 + quad * 4 + rg;
        if(row < B_SZ) atomicAdd(&pp[row], (float)c);
      }
    }
}

// ---------------- out[b] = 1 + sum of 8 parts ------------------------------
__global__ void final_kernel(const float* __restrict__ part, float* __restrict__ out){
  int b = blockIdx.x * 256 + threadIdx.x;
  if(b >= B_SZ) return;
  float s = 1.0f;
  #pragma unroll
  for(int p = 0; p < 8; p++) s += part[p * 1024 + b];
  out[b] = s;
}

extern "C" void kernel_launch(void* const* d_in, const int* in_sizes, int n_in,
                              void* d_out, int out_size, void* d_ws, size_t ws_size,
                              hipStream_t stream){
  const float* q    = (const float*)d_in[0];
  const float* rhs  = (const float*)d_in[1];
  const int* filt   = (const int*)d_in[2];
  const int* target = (const int*)d_in[3];
  float* out = (float*)d_out;
  char* ws = (char*)d_ws;
  float* part       = (float*)(ws + PART_OFF);
  int* cnt          = (int*)(ws + CNT_OFF);
  float* t          = (float*)(ws + T_OFF);
  unsigned* entries = (unsigned*)(ws + ENT_OFF);
  __bf16* qb        = (__bf16*)(ws + QB_OFF);
  // ws use: 2 MB

  zero_ws<<<40, 256, 0, stream>>>((int*)ws);                 // part + cnt
  cvtq_kernel<<<256, 256, 0, stream>>>(q, qb);
  t_kernel<<<B_SZ, 256, 0, stream>>>(q, rhs, target, t);
  prep_kernel<<<(B_SZ + 255) / 256, 256, 0, stream>>>(filt, target, cnt, entries);
  main_kernel<<<dim3(2, NB), 512, 0, stream>>>(rhs, qb, t, cnt, entries, part);
  final_kernel<<<4, 256, 0, stream>>>(part, out);
}